// Round 1
// 132.106 us; speedup vs baseline: 1.0194x; 1.0194x over previous
//
#include <hip/hip_runtime.h>
#include <hip/hip_bf16.h>

// Problem constants (from reference setup_inputs)
constexpr int K    = 64;
constexpr int N    = 1024;
constexpr int DIN  = 16;
constexpr int H1   = 4;
constexpr int DOUT = 8;
constexpr int FC1  = 54;

#define ALPHA_F   (0.01f)
#define LOG2E_F   (1.4426950408889634f)

typedef unsigned int uint;
typedef short  bf16x8 __attribute__((ext_vector_type(8)));
typedef float  f32x4  __attribute__((ext_vector_type(4)));

__device__ inline float fast_exp2(float x) {
#if __has_builtin(__builtin_amdgcn_exp2f)
    return __builtin_amdgcn_exp2f(x);      // raw v_exp_f32
#else
    return __expf(x * 0.6931471805599453f);
#endif
}

// packed bf16 pair (RNE) -> uint (lo=a, hi=b); v_cvt_pk_bf16_f32 on gfx950
__device__ inline uint pk_bf16(float a, float b) {
    union { __hip_bfloat162 h; uint u; } v;
    v.h = __float22bfloat162_rn(make_float2(a, b));
    return v.u;
}

// ---------------------------------------------------------------------------
// B-fragment table layout (consumed by mfma_f32_16x16x32_bf16):
//   HB[k][c][lane] : uint4;  lane=(q=lane>>4, n=lane&15)
//   dword t packs rows j=c*32+q*8+2t, +2t+1 of column n:
//   n<F -> bf16(h[j][n]); n==F -> 1.0 (denominator column); n>F -> 0.
// ---------------------------------------------------------------------------

// ---------------------------------------------------------------------------
// prep kernel: two independent jobs split by blockIdx range.
//  A) blocks [0,2048):    maskM[i*16+jw] = ballot bits of adj[i][jw*64+lane]
//                         (ROW-major words: byte b of row i covers j=8b..8b+7)
//  B) blocks [2048,2176): gat1 proj h=X@W1 -> f11/f21 logits (*log2e) AND
//                         HB1 bf16 B-fragment table (via LDS row-stage)
// ---------------------------------------------------------------------------
__global__ __launch_bounds__(512) void prep_kernel(
        const int* __restrict__ adj, unsigned long long* __restrict__ maskM,
        const float* __restrict__ X, const float* __restrict__ W1,
        const float* __restrict__ a1,
        uint4* __restrict__ HB1, float* __restrict__ f11, float* __restrict__ f21) {
    int b = blockIdx.x;
    if (b < 2048) {
        int wave = threadIdx.x >> 6, lane = threadIdx.x & 63;
        int wid = b * 8 + wave;            // 0..16383
        int jw  = wid >> 10;               // 0..15
        int i   = wid & 1023;
        int v = adj[i * N + (jw << 6) + lane];        // coalesced 256B/wave
        unsigned long long m = __ballot(v > 0);       // bit lane = adj>0
        if (lane == 0) maskM[i * 16 + jw] = m;        // row-major
    } else {
        __shared__ float hrow[512 * 4];               // 8 KB row-stage
        const int bb  = b - 2048;                     // 0..127
        const int k   = bb >> 1;
        const int j0  = (bb & 1) * 512;
        const int tid = threadIdx.x;
        const int idx = k * N + j0 + tid;             // this thread's (k,j)
        const float4* x4 = (const float4*)(X + (size_t)idx * DIN);
        float hv_[H1] = {0.f, 0.f, 0.f, 0.f};
        #pragma unroll
        for (int q = 0; q < 4; q++) {
            float4 xv = x4[q];
            #pragma unroll
            for (int f = 0; f < H1; f++) {
                hv_[f] += xv.x * W1[(q * 4 + 0) * H1 + f] + xv.y * W1[(q * 4 + 1) * H1 + f]
                        + xv.z * W1[(q * 4 + 2) * H1 + f] + xv.w * W1[(q * 4 + 3) * H1 + f];
            }
        }
        float s1 = 0.f, s2 = 0.f;
        #pragma unroll
        for (int f = 0; f < H1; f++) { s1 += hv_[f] * a1[f]; s2 += hv_[f] * a1[H1 + f]; }
        f11[idx] = s1 * LOG2E_F;
        f21[idx] = s2 * LOG2E_F;
        #pragma unroll
        for (int f = 0; f < H1; f++) hrow[tid * 4 + f] = hv_[f];
        __syncthreads();
        // frag writes: local chunks cl=0..15 -> global chunks j0/32+cl
        uint4* HBk = HB1 + (size_t)k * 2048 + (j0 >> 5) * 64;
        #pragma unroll
        for (int e = tid; e < 1024; e += 512) {
            int cl = e >> 6, l = e & 63, q = (l >> 4), n = l & 15;
            uint4 dw;
            if (n < H1) {
                const float* hp = hrow + (cl * 32 + q * 8) * 4 + n;
                dw.x = pk_bf16(hp[0],  hp[4]);
                dw.y = pk_bf16(hp[8],  hp[12]);
                dw.z = pk_bf16(hp[16], hp[20]);
                dw.w = pk_bf16(hp[24], hp[28]);
            } else if (n == H1) {
                dw = make_uint4(0x3f803f80u, 0x3f803f80u, 0x3f803f80u, 0x3f803f80u);
            } else {
                dw = make_uint4(0u, 0u, 0u, 0u);
            }
            HBk[cl * 64 + l] = dw;
        }
    }
}

// ---------------------------------------------------------------------------
// MFMA attention v3: B-fragments from GLOBAL (coalesced VMEM, L2-resident
// 2 MB table) — no per-block H staging, no staging barrier; LDS carries only
// f2 (4 KB, quad-broadcast reads).  P[16x32] built per chunk in A-fragment
// layout; ones-column in HB gives the denominator in acc col F.
// Block 512 thr = 8 waves = 8 i-tiles; grid K*8.
// FUSE (layer 1): epilogue computes layer-2 projection AND writes the HB2
// fragment table directly (wave-local LDS transpose), plus f12/f22.
// ---------------------------------------------------------------------------
template <int F, bool FUSE>
__global__ __launch_bounds__(512, 4) void gat_attn_mfma(
        const unsigned long long* __restrict__ maskM,  // [N][16] row-major
        const uint4* __restrict__ HBin,  // [K][32][64] B-frags
        const float* __restrict__ f1,    // [K,N]  (x log2e)
        const float* __restrict__ f2,    // [K,N]  (x log2e)
        const float* __restrict__ W2,    // [4,8]  (FUSE only)
        const float* __restrict__ a2,    // [16]   (FUSE only)
        uint4* __restrict__ HBout,       // FUSE: HB2 table
        float* __restrict__ o_x,         // !FUSE: out rows [K,N,F]
        float* __restrict__ o_f1,        // FUSE: f12 (x log2e)
        float* __restrict__ o_f2) {      // FUSE: f22 (x log2e)
    __shared__ float F2s[1024];          // f2[k] (4 KB)
    __shared__ float XPa[8][16][5];      // FUSE: attn output xo
    __shared__ float XPb[8][16][9];      // FUSE: projected hv

    const int tid  = threadIdx.x;
    const int lane = tid & 63;
    const int wv   = tid >> 6;
    const int quad = lane >> 4;
    const int n16  = lane & 15;
    const int k    = blockIdx.x >> 3;

    if (tid < 256)
        ((float4*)F2s)[tid] = ((const float4*)(f2 + k * N))[tid];
    __syncthreads();

    const int itile = (blockIdx.x & 7) * 8 + wv;     // 0..63
    const int ibase = itile * 16;
    const int irow  = ibase + n16;                   // this lane's P row
    const float f1v = f1[k * N + irow];
    const uint4* mrow = (const uint4*)((const char*)maskM + (size_t)irow * 128);
    const uint4* HBk  = HBin + (size_t)k * 2048;

    f32x4 acc = {0.f, 0.f, 0.f, 0.f};
    union { bf16x8 v; uint u[4]; } af;
    union { bf16x8 v; uint4 q; }  bfrag;

    #pragma unroll 2
    for (int g = 0; g < 8; g++) {
        const uint4 Mg = mrow[g];                    // 4 chunks of mask bits
        #pragma unroll
        for (int cc = 0; cc < 4; cc++) {
            const int c = g * 4 + cc;
            const uint mdw = (cc == 0) ? Mg.x : (cc == 1) ? Mg.y
                           : (cc == 2) ? Mg.z : Mg.w;
            const uint mb  = (mdw >> (quad * 8)) & 0xffu;  // 8 bits, this lane
            float4 fa = *(const float4*)(F2s + c * 32 + quad * 8);
            float4 fb = *(const float4*)(F2s + c * 32 + quad * 8 + 4);
            bfrag.q = HBk[c * 64 + lane];            // coalesced VMEM (L2)
            float f2e[8] = {fa.x, fa.y, fa.z, fa.w, fb.x, fb.y, fb.z, fb.w};
            float pv[8];
            #pragma unroll
            for (int jj = 0; jj < 8; jj++) {
                float x = f1v + f2e[jj];
                float e = fmaxf(x, ALPHA_F * x);     // leaky (log2-scaled)
                float p = fast_exp2(e);
                pv[jj] = (mb & (1u << jj)) ? p : 0.f;  // mask -> exact 0
            }
            #pragma unroll
            for (int pr = 0; pr < 4; pr++)
                af.u[pr] = pk_bf16(pv[2 * pr], pv[2 * pr + 1]);
            acc = __builtin_amdgcn_mfma_f32_16x16x32_bf16(af.v, bfrag.v, acc, 0, 0, 0);
        }
    }

    // ---- epilogue: C[m][n]: n=lane&15, m=quad*4+reg; denom in col n==F ----
    #pragma unroll
    for (int r = 0; r < 4; r++) {
        float den = __shfl(acc[r], (lane & 48) + F);
        float inv = (den > 0.f) ? 1.f / den : 0.f;
        float xo  = fmaxf(acc[r] * inv, 0.f);        // relu
        int m = quad * 4 + r;
        if constexpr (FUSE) {
            if (n16 < F) XPa[wv][m][n16] = xo;
        } else {
            if (n16 < F) o_x[((size_t)k * N + ibase + m) * F + n16] = xo;
        }
    }

    if constexpr (FUSE) {
        __syncthreads();
        if (lane < 16) {
            const int m = lane;
            float x0 = XPa[wv][m][0], x1 = XPa[wv][m][1];
            float x2v = XPa[wv][m][2], x3 = XPa[wv][m][3];
            float hv[DOUT];
            #pragma unroll
            for (int f = 0; f < DOUT; f++) {
                hv[f] = x0 * W2[f]      + x1 * W2[8 + f]
                      + x2v * W2[16 + f] + x3 * W2[24 + f];
            }
            float t1 = 0.f, t2 = 0.f;
            #pragma unroll
            for (int f = 0; f < DOUT; f++) { t1 += hv[f] * a2[f]; t2 += hv[f] * a2[DOUT + f]; }
            const int row = k * N + ibase + m;
            o_f1[row] = t1 * LOG2E_F;
            o_f2[row] = t2 * LOG2E_F;
            #pragma unroll
            for (int f = 0; f < DOUT; f++) XPb[wv][m][f] = hv[f];
        }
        __syncthreads();
        if (lane < 32) {
            const int c2    = ibase >> 5;
            const int qhalf = (ibase >> 4) & 1;
            const int ql    = lane >> 4;
            const int n     = lane & 15;
            const int q     = qhalf * 2 + ql;
            uint4 dw;
            if (n < DOUT) {
                dw.x = pk_bf16(XPb[wv][ql * 8 + 0][n], XPb[wv][ql * 8 + 1][n]);
                dw.y = pk_bf16(XPb[wv][ql * 8 + 2][n], XPb[wv][ql * 8 + 3][n]);
                dw.z = pk_bf16(XPb[wv][ql * 8 + 4][n], XPb[wv][ql * 8 + 5][n]);
                dw.w = pk_bf16(XPb[wv][ql * 8 + 6][n], XPb[wv][ql * 8 + 7][n]);
            } else if (n == DOUT) {
                dw = make_uint4(0x3f803f80u, 0x3f803f80u, 0x3f803f80u, 0x3f803f80u);
            } else {
                dw = make_uint4(0u, 0u, 0u, 0u);
            }
            HBout[(size_t)k * 2048 + c2 * 64 + q * 16 + n] = dw;
        }
    }
}

// ---------------------------------------------------------------------------
// FC1 split-K: yp[s][k][c] = sum_{m in slab s} x2[k][m] * fc1w[m][c]
// Grid 256 blocks = (kt 8-k tile) x (s: 32 m-slabs of 256), 256 threads.
// fc1w slab staged contiguously into LDS (no transpose needed at all);
// x2 tile (8 rows x 256) staged into LDS.  Per lane: c = t&63 (54 active),
// 2 k-rows.  ws reads are 2-way bank-aliased (free); xs reads wave-uniform
// broadcasts.  Total traffic ~16 MB vs 221 MB for the per-(k,c)-block GEMV.
// No atomics; fc2 reduces the 32 partials.
// ---------------------------------------------------------------------------
__global__ __launch_bounds__(256) void fc1_kernel(
        const float* __restrict__ x2, const float* __restrict__ fc1w,
        float* __restrict__ yp) {
    __shared__ float ws[256 * FC1];       // 13824 floats = 54 KB
    __shared__ float xs[8 * 256];         // 8 KB
    const int t  = threadIdx.x;
    const int bx = blockIdx.x;
    const int kt = bx & 7;                // which 8-row k-tile
    const int s  = bx >> 3;               // which 256-wide m-slab
    const int m0 = s << 8;
    const int k0 = kt << 3;

    // stage fc1w[m0..m0+256)[0..54): contiguous 13824 floats
    const float4* wsrc = (const float4*)(fc1w + (size_t)m0 * FC1);
    float4* ws4 = (float4*)ws;
    #pragma unroll
    for (int i = t; i < (256 * FC1) / 4; i += 256) ws4[i] = wsrc[i];

    // stage x2 rows k0..k0+7, cols m0..m0+255 (each row 64 float4, coalesced)
    {
        float4* xs4 = (float4*)xs;
        const int r = t >> 6, col = t & 63;
        #pragma unroll
        for (int rr = 0; rr < 8; rr += 4)
            xs4[(r + rr) * 64 + col] =
                ((const float4*)(x2 + (size_t)(k0 + r + rr) * (N * DOUT) + m0))[col];
    }
    __syncthreads();

    const int c    = t & 63;
    const int kq   = t >> 6;              // 0..3 -> rows kq*2, kq*2+1
    const int ceff = (c < FC1) ? c : 0;   // keep idle lanes in-bounds/finite
    const float* xa = xs + (kq * 2) * 256;
    const float* xb = xa + 256;
    float acc0 = 0.f, acc1 = 0.f;
    #pragma unroll 8
    for (int m = 0; m < 256; m++) {
        float w = ws[m * FC1 + ceff];
        acc0 += w * xa[m];
        acc1 += w * xb[m];
    }
    float* yrow = yp + ((size_t)s * 64 + k0 + kq * 2) * 64 + c;  // [s][k][64]
    yrow[0]  = acc0;
    yrow[64] = acc1;
}

// ---------------------------------------------------------------------------
// FC2 fused: reduce the 32 fc1 partials, + bias, relu -> ybuf[54] in LDS,
// then out[k,n] = ybuf . out_w[:,n] + out_b[n].
// Grid (2, K): blockIdx.x = n-half, blockIdx.y = k.  512 threads.
// ---------------------------------------------------------------------------
__global__ __launch_bounds__(512) void fc2_kernel(
        const float* __restrict__ yp, const float* __restrict__ fc1b,
        const float* __restrict__ outw, const float* __restrict__ outb,
        float* __restrict__ out) {
    __shared__ float red[512];
    __shared__ float ybuf[FC1];
    const int t = threadIdx.x;
    const int k = blockIdx.y;
    const int c = t & 63, sg = t >> 6;    // sg = 0..7
    float v = 0.f;
    #pragma unroll
    for (int j = 0; j < 4; j++)           // s = sg, sg+8, sg+16, sg+24
        v += yp[((size_t)(sg + 8 * j) * 64 + k) * 64 + c];
    red[t] = v;
    __syncthreads();
    if (t < FC1) {
        float s = fc1b[t];
        #pragma unroll
        for (int g = 0; g < 8; g++) s += red[g * 64 + t];
        ybuf[t] = fmaxf(s, 0.f);          // bias + relu folded here
    }
    __syncthreads();
    const int n = blockIdx.x * 512 + t;   // 0..1023
    float s = outb[n];
    #pragma unroll 6
    for (int cc = 0; cc < FC1; cc++)
        s += ybuf[cc] * outw[(size_t)cc * N + n];
    out[(size_t)k * N + n] = s;
}

// ---------------------------------------------------------------------------
extern "C" void kernel_launch(void* const* d_in, const int* in_sizes, int n_in,
                              void* d_out, int out_size, void* d_ws, size_t ws_size,
                              hipStream_t stream) {
    const float* X     = (const float*)d_in[0];
    const int*   adj   = (const int*)  d_in[1];
    const float* W1    = (const float*)d_in[2];
    const float* a1    = (const float*)d_in[3];
    const float* W2    = (const float*)d_in[4];
    const float* a2    = (const float*)d_in[5];
    const float* fc1w  = (const float*)d_in[6];
    const float* fc1b  = (const float*)d_in[7];
    const float* outw  = (const float*)d_in[8];
    const float* outb  = (const float*)d_in[9];
    float* out = (float*)d_out;

    // Workspace layout (floats); ~8.0 MB total
    float* ws  = (float*)d_ws;
    float* f11 = ws;                       // 65536
    float* f21 = f11 + 65536;              // 65536
    float* f12 = f21 + 65536;              // 65536
    float* f22 = f12 + 65536;              // 65536
    float* x2  = f22 + 65536;              // 524288
    float* yp  = x2  + 524288;             // 131072 (32 x 64 x 64 partials)
    unsigned long long* mM = (unsigned long long*)(yp + 131072);   // 16384 u64
    uint4* HB1 = (uint4*)(yp + 131072 + 32768);                    // 131072 u4
    uint4* HB2 = HB1 + 131072;                                     // 131072 u4

    // 1) fused prep: mask pack + gat1 proj -> HB1 frags (transpose job gone)
    prep_kernel<<<dim3(2176), dim3(512), 0, stream>>>(
        adj, mM, X, W1, a1, HB1, f11, f21);

    // 2) layer-1 attention (MFMA, global frags) -> HB2 frags + f12/f22
    gat_attn_mfma<4, true><<<dim3(K * 8), dim3(512), 0, stream>>>(
        mM, HB1, f11, f21, W2, a2, HB2, nullptr, f12, f22);

    // 3) layer-2 attention (MFMA, global frags) -> x2 rows
    gat_attn_mfma<8, false><<<dim3(K * 8), dim3(512), 0, stream>>>(
        mM, HB2, f12, f22, nullptr, nullptr, nullptr, x2, nullptr, nullptr);

    // 4) FC1 split-K partials (fc1w read exactly once, staged via LDS)
    fc1_kernel<<<dim3(256), dim3(256), 0, stream>>>(x2, fc1w, yp);

    // 5) FC2: partial-reduce + bias + relu + output GEMV
    fc2_kernel<<<dim3(2, K), dim3(512), 0, stream>>>(yp, fc1b, outw, outb, out);
}

// Round 2
// 124.816 us; speedup vs baseline: 1.0789x; 1.0584x over previous
//
#include <hip/hip_runtime.h>
#include <hip/hip_bf16.h>

// Problem constants (from reference setup_inputs)
constexpr int K    = 64;
constexpr int N    = 1024;
constexpr int DIN  = 16;
constexpr int H1   = 4;
constexpr int DOUT = 8;
constexpr int FC1  = 54;

#define ALPHA_F   (0.01f)
#define LOG2E_F   (1.4426950408889634f)

typedef unsigned int uint;
typedef short  bf16x8 __attribute__((ext_vector_type(8)));
typedef float  f32x4  __attribute__((ext_vector_type(4)));

__device__ inline float fast_exp2(float x) {
#if __has_builtin(__builtin_amdgcn_exp2f)
    return __builtin_amdgcn_exp2f(x);      // raw v_exp_f32
#else
    return __expf(x * 0.6931471805599453f);
#endif
}

// packed bf16 pair (RNE) -> uint (lo=a, hi=b); v_cvt_pk_bf16_f32 on gfx950
__device__ inline uint pk_bf16(float a, float b) {
    union { __hip_bfloat162 h; uint u; } v;
    v.h = __float22bfloat162_rn(make_float2(a, b));
    return v.u;
}

// ---------------------------------------------------------------------------
// B-fragment table layout (consumed by mfma_f32_16x16x32_bf16):
//   HB[k][c][lane] : uint4;  lane=(q=lane>>4, n=lane&15)
//   dword t packs rows j=c*32+q*8+2t, +2t+1 of column n:
//   n<F -> bf16(h[j][n]); n==F -> 1.0 (denominator column); n>F -> 0.
// ---------------------------------------------------------------------------

// ---------------------------------------------------------------------------
// prep kernel: three jobs split by blockIdx range.
//  A) blocks [0,512):    maskM pack: each wave handles 4 (i,jw) units
//                        (ROW-major words: byte b of row i covers j=8b..8b+7)
//  B) blocks [512,640):  gat1 proj h=X@W1 -> f11/f21 logits (*log2e) AND
//                        HB1 bf16 B-fragment table (via LDS row-stage)
//  C) block 640:         zero y accumulator (for attn2 fc1-partial atomics)
// ---------------------------------------------------------------------------
__global__ __launch_bounds__(512) void prep_kernel(
        const int* __restrict__ adj, unsigned long long* __restrict__ maskM,
        const float* __restrict__ X, const float* __restrict__ W1,
        const float* __restrict__ a1,
        uint4* __restrict__ HB1, float* __restrict__ f11, float* __restrict__ f21,
        float* __restrict__ y) {
    int b = blockIdx.x;
    if (b < 512) {
        int wv = threadIdx.x >> 6, lane = threadIdx.x & 63;
        int g = b * 8 + wv;                // 0..4095
        #pragma unroll
        for (int uu = 0; uu < 4; uu++) {
            int u = g * 4 + uu;            // 0..16383
            int jw = u >> 10;              // 0..15
            int i  = u & 1023;
            int v = adj[i * N + (jw << 6) + lane];    // coalesced 256B/wave
            unsigned long long m = __ballot(v > 0);   // bit lane = adj>0
            if (lane == 0) maskM[i * 16 + jw] = m;    // row-major
        }
    } else if (b < 640) {
        __shared__ float hrow[512 * 4];               // 8 KB row-stage
        const int bb  = b - 512;                      // 0..127
        const int k   = bb >> 1;
        const int j0  = (bb & 1) * 512;
        const int tid = threadIdx.x;
        const int idx = k * N + j0 + tid;             // this thread's (k,j)
        const float4* x4 = (const float4*)(X + (size_t)idx * DIN);
        float hv_[H1] = {0.f, 0.f, 0.f, 0.f};
        #pragma unroll
        for (int q = 0; q < 4; q++) {
            float4 xv = x4[q];
            #pragma unroll
            for (int f = 0; f < H1; f++) {
                hv_[f] += xv.x * W1[(q * 4 + 0) * H1 + f] + xv.y * W1[(q * 4 + 1) * H1 + f]
                        + xv.z * W1[(q * 4 + 2) * H1 + f] + xv.w * W1[(q * 4 + 3) * H1 + f];
            }
        }
        float s1 = 0.f, s2 = 0.f;
        #pragma unroll
        for (int f = 0; f < H1; f++) { s1 += hv_[f] * a1[f]; s2 += hv_[f] * a1[H1 + f]; }
        f11[idx] = s1 * LOG2E_F;
        f21[idx] = s2 * LOG2E_F;
        #pragma unroll
        for (int f = 0; f < H1; f++) hrow[tid * 4 + f] = hv_[f];
        __syncthreads();
        // frag writes: local chunks cl=0..15 -> global chunks j0/32+cl
        uint4* HBk = HB1 + (size_t)k * 2048 + (j0 >> 5) * 64;
        #pragma unroll
        for (int e = tid; e < 1024; e += 512) {
            int cl = e >> 6, l = e & 63, q = (l >> 4), n = l & 15;
            uint4 dw;
            if (n < H1) {
                const float* hp = hrow + (cl * 32 + q * 8) * 4 + n;
                dw.x = pk_bf16(hp[0],  hp[4]);
                dw.y = pk_bf16(hp[8],  hp[12]);
                dw.z = pk_bf16(hp[16], hp[20]);
                dw.w = pk_bf16(hp[24], hp[28]);
            } else if (n == H1) {
                dw = make_uint4(0x3f803f80u, 0x3f803f80u, 0x3f803f80u, 0x3f803f80u);
            } else {
                dw = make_uint4(0u, 0u, 0u, 0u);
            }
            HBk[cl * 64 + l] = dw;
        }
    } else {
        // zero the fc1 atomic accumulator
        for (int t = threadIdx.x; t < 4096; t += 512) y[t] = 0.f;
    }
}

// ---------------------------------------------------------------------------
// MFMA attention v3: B-fragments from GLOBAL (coalesced VMEM, L2-resident
// 2 MB table) — no per-block H staging; LDS carries only f2 (4 KB,
// quad-broadcast reads).  P[16x32] built per chunk in A-fragment layout;
// ones-column in HB gives the denominator in acc col F.
// Block 512 thr = 8 waves = 8 i-tiles; grid K*8.
// FUSE (layer 1): epilogue computes layer-2 projection AND writes the HB2
// fragment table directly (wave-local LDS transpose), plus f12/f22.
// !FUSE (layer 2): epilogue computes per-wave fc1 partials over its 16x8
// output tile and atomically accumulates into y[k][54] (x2 never hits HBM).
// ---------------------------------------------------------------------------
template <int F, bool FUSE>
__global__ __launch_bounds__(512, 4) void gat_attn_mfma(
        const unsigned long long* __restrict__ maskM,  // [N][16] row-major
        const uint4* __restrict__ HBin,  // [K][32][64] B-frags
        const float* __restrict__ f1,    // [K,N]  (x log2e)
        const float* __restrict__ f2,    // [K,N]  (x log2e)
        const float* __restrict__ W2,    // [4,8]  (FUSE only)
        const float* __restrict__ a2,    // [16]   (FUSE only)
        const float* __restrict__ fc1w,  // [8192,54] (!FUSE only)
        uint4* __restrict__ HBout,       // FUSE: HB2 table
        float* __restrict__ y,           // !FUSE: fc1 partial accumulator [K,54]
        float* __restrict__ o_f1,        // FUSE: f12 (x log2e)
        float* __restrict__ o_f2) {      // FUSE: f22 (x log2e)
    __shared__ float F2s[1024];          // f2[k] (4 KB)
    __shared__ float XPa[8][16][5];      // FUSE: attn output xo
    __shared__ float XPb[8][16][9];      // FUSE: projected hv / !FUSE: xo tile
    __shared__ float YPs[8][64];         // !FUSE: per-wave fc1 partials

    const int tid  = threadIdx.x;
    const int lane = tid & 63;
    const int wv   = tid >> 6;
    const int quad = lane >> 4;
    const int n16  = lane & 15;
    const int k    = blockIdx.x >> 3;

    if (tid < 256)
        ((float4*)F2s)[tid] = ((const float4*)(f2 + k * N))[tid];
    __syncthreads();

    const int itile = (blockIdx.x & 7) * 8 + wv;     // 0..63
    const int ibase = itile * 16;
    const int irow  = ibase + n16;                   // this lane's P row
    const float f1v = f1[k * N + irow];
    const uint4* mrow = (const uint4*)((const char*)maskM + (size_t)irow * 128);
    const uint4* HBk  = HBin + (size_t)k * 2048;

    f32x4 acc = {0.f, 0.f, 0.f, 0.f};
    union { bf16x8 v; uint u[4]; } af;
    union { bf16x8 v; uint4 q; }  bfrag;

    #pragma unroll 2
    for (int g = 0; g < 8; g++) {
        const uint4 Mg = mrow[g];                    // 4 chunks of mask bits
        #pragma unroll
        for (int cc = 0; cc < 4; cc++) {
            const int c = g * 4 + cc;
            const uint mdw = (cc == 0) ? Mg.x : (cc == 1) ? Mg.y
                           : (cc == 2) ? Mg.z : Mg.w;
            const uint mb  = (mdw >> (quad * 8)) & 0xffu;  // 8 bits, this lane
            float4 fa = *(const float4*)(F2s + c * 32 + quad * 8);
            float4 fb = *(const float4*)(F2s + c * 32 + quad * 8 + 4);
            bfrag.q = HBk[c * 64 + lane];            // coalesced VMEM (L2)
            float f2e[8] = {fa.x, fa.y, fa.z, fa.w, fb.x, fb.y, fb.z, fb.w};
            float pv[8];
            #pragma unroll
            for (int jj = 0; jj < 8; jj++) {
                float x = f1v + f2e[jj];
                float e = fmaxf(x, ALPHA_F * x);     // leaky (log2-scaled)
                float p = fast_exp2(e);
                pv[jj] = (mb & (1u << jj)) ? p : 0.f;  // mask -> exact 0
            }
            #pragma unroll
            for (int pr = 0; pr < 4; pr++)
                af.u[pr] = pk_bf16(pv[2 * pr], pv[2 * pr + 1]);
            acc = __builtin_amdgcn_mfma_f32_16x16x32_bf16(af.v, bfrag.v, acc, 0, 0, 0);
        }
    }

    // ---- epilogue: C[m][n]: n=lane&15, m=quad*4+reg; denom in col n==F ----
    #pragma unroll
    for (int r = 0; r < 4; r++) {
        float den = __shfl(acc[r], (lane & 48) + F);
        float inv = (den > 0.f) ? 1.f / den : 0.f;
        float xo  = fmaxf(acc[r] * inv, 0.f);        // relu
        int m = quad * 4 + r;
        if constexpr (FUSE) {
            if (n16 < F) XPa[wv][m][n16] = xo;
        } else {
            if (n16 < F) XPb[wv][m][n16] = xo;       // wave-local stage
        }
    }

    if constexpr (FUSE) {
        __syncthreads();
        if (lane < 16) {
            const int m = lane;
            float x0 = XPa[wv][m][0], x1 = XPa[wv][m][1];
            float x2v = XPa[wv][m][2], x3 = XPa[wv][m][3];
            float hv[DOUT];
            #pragma unroll
            for (int f = 0; f < DOUT; f++) {
                hv[f] = x0 * W2[f]      + x1 * W2[8 + f]
                      + x2v * W2[16 + f] + x3 * W2[24 + f];
            }
            float t1 = 0.f, t2 = 0.f;
            #pragma unroll
            for (int f = 0; f < DOUT; f++) { t1 += hv[f] * a2[f]; t2 += hv[f] * a2[DOUT + f]; }
            const int row = k * N + ibase + m;
            o_f1[row] = t1 * LOG2E_F;
            o_f2[row] = t2 * LOG2E_F;
            #pragma unroll
            for (int f = 0; f < DOUT; f++) XPb[wv][m][f] = hv[f];
        }
        __syncthreads();
        if (lane < 32) {
            const int c2    = ibase >> 5;
            const int qhalf = (ibase >> 4) & 1;
            const int ql    = lane >> 4;
            const int n     = lane & 15;
            const int q     = qhalf * 2 + ql;
            uint4 dw;
            if (n < DOUT) {
                dw.x = pk_bf16(XPb[wv][ql * 8 + 0][n], XPb[wv][ql * 8 + 1][n]);
                dw.y = pk_bf16(XPb[wv][ql * 8 + 2][n], XPb[wv][ql * 8 + 3][n]);
                dw.z = pk_bf16(XPb[wv][ql * 8 + 4][n], XPb[wv][ql * 8 + 5][n]);
                dw.w = pk_bf16(XPb[wv][ql * 8 + 6][n], XPb[wv][ql * 8 + 7][n]);
            } else if (n == DOUT) {
                dw = make_uint4(0x3f803f80u, 0x3f803f80u, 0x3f803f80u, 0x3f803f80u);
            } else {
                dw = make_uint4(0u, 0u, 0u, 0u);
            }
            HBout[(size_t)k * 2048 + c2 * 64 + q * 16 + n] = dw;
        }
    } else {
        // ---- fused fc1: per-wave partial over this wave's 128 x2-columns ----
        // x2[k][m] for m = ibase*8 + mm, mm = lr*8 + f, lives in XPb[wv][lr][f]
        // (wave-local LDS: same wave wrote it, lgkmcnt ordering suffices).
        const int ceff = (lane < FC1) ? lane : 0;    // c = lane (54 active)
        const float* wb = fc1w + (size_t)ibase * DOUT * FC1;
        float pacc = 0.f;
        #pragma unroll 8
        for (int mm = 0; mm < 128; mm++) {
            float xv = XPb[wv][mm >> 3][mm & 7];     // wave-uniform broadcast
            pacc = fmaf(xv, wb[(size_t)mm * FC1 + ceff], pacc);
        }
        YPs[wv][lane] = pacc;
        __syncthreads();
        if (tid < 64) {
            float s = 0.f;
            #pragma unroll
            for (int w = 0; w < 8; w++) s += YPs[w][tid];
            if (tid < FC1) atomicAdd(&y[k * FC1 + tid], s);
        }
    }
}

// ---------------------------------------------------------------------------
// FC2 fused: bias + relu on the atomic-accumulated fc1 sums -> ybuf[54] in
// LDS, then out[k,n] = ybuf . out_w[:,n] + out_b[n].
// Grid (2, K): blockIdx.x = n-half, blockIdx.y = k.  512 threads.
// ---------------------------------------------------------------------------
__global__ __launch_bounds__(512) void fc2_kernel(
        const float* __restrict__ y, const float* __restrict__ fc1b,
        const float* __restrict__ outw, const float* __restrict__ outb,
        float* __restrict__ out) {
    __shared__ float ybuf[FC1];
    const int t = threadIdx.x;
    const int k = blockIdx.y;
    if (t < FC1) ybuf[t] = fmaxf(y[k * FC1 + t] + fc1b[t], 0.f);
    __syncthreads();
    const int n = blockIdx.x * 512 + t;   // 0..1023
    float s = outb[n];
    #pragma unroll 6
    for (int cc = 0; cc < FC1; cc++)
        s += ybuf[cc] * outw[(size_t)cc * N + n];
    out[(size_t)k * N + n] = s;
}

// ---------------------------------------------------------------------------
extern "C" void kernel_launch(void* const* d_in, const int* in_sizes, int n_in,
                              void* d_out, int out_size, void* d_ws, size_t ws_size,
                              hipStream_t stream) {
    const float* X     = (const float*)d_in[0];
    const int*   adj   = (const int*)  d_in[1];
    const float* W1    = (const float*)d_in[2];
    const float* a1    = (const float*)d_in[3];
    const float* W2    = (const float*)d_in[4];
    const float* a2    = (const float*)d_in[5];
    const float* fc1w  = (const float*)d_in[6];
    const float* fc1b  = (const float*)d_in[7];
    const float* outw  = (const float*)d_in[8];
    const float* outb  = (const float*)d_in[9];
    float* out = (float*)d_out;

    // Workspace layout (floats); ~5.3 MB total
    float* ws  = (float*)d_ws;
    float* f11 = ws;                       // 65536
    float* f21 = f11 + 65536;              // 65536
    float* f12 = f21 + 65536;              // 65536
    float* f22 = f12 + 65536;              // 65536
    float* y   = f22 + 65536;              // 4096 (3456 used; atomic acc)
    unsigned long long* mM = (unsigned long long*)(y + 4096);      // 16384 u64
    uint4* HB1 = (uint4*)(y + 4096 + 32768);                       // 131072 u4
    uint4* HB2 = HB1 + 131072;                                     // 131072 u4

    // 1) fused prep: mask pack + gat1 proj -> HB1 frags + zero y
    prep_kernel<<<dim3(641), dim3(512), 0, stream>>>(
        adj, mM, X, W1, a1, HB1, f11, f21, y);

    // 2) layer-1 attention (MFMA, global frags) -> HB2 frags + f12/f22
    gat_attn_mfma<4, true><<<dim3(K * 8), dim3(512), 0, stream>>>(
        mM, HB1, f11, f21, W2, a2, nullptr, HB2, nullptr, f12, f22);

    // 3) layer-2 attention -> fused fc1 partials (atomicAdd into y)
    gat_attn_mfma<8, false><<<dim3(K * 8), dim3(512), 0, stream>>>(
        mM, HB2, f12, f22, nullptr, nullptr, fc1w, nullptr, y, nullptr, nullptr);

    // 4) FC2: bias + relu + output GEMV
    fc2_kernel<<<dim3(2, K), dim3(512), 0, stream>>>(y, fc1b, outw, outb, out);
}